// Round 11
// baseline (2381.891 us; speedup 1.0000x reference)
//
#include <hip/hip_runtime.h>
#include <cstddef>

#define B_   8
#define N_   8192
#define M_   2048
#define K_   32
#define DIN_ 13

typedef _Float16 f16x8 __attribute__((ext_vector_type(8)));
typedef float    f32x4 __attribute__((ext_vector_type(4)));

// DPP-assisted max step: combine v with the value DPP-moved from another lane.
// Invalid source lanes yield old = -inf (identity for max). VALU-pipe only.
template <int CTRL>
__device__ __forceinline__ float dppmax(float v) {
  int o = __builtin_amdgcn_update_dpp(
      (int)0xff800000, __float_as_int(v), CTRL, 0xF, 0xF, false);
  return fmaxf(v, __int_as_float(o));
}

// ---------------------------------------------------------------------------
// Kernel 1: farthest point sampling. r11 DISCRIMINATING EXPERIMENT:
// 256 threads/block (4 waves), 32 pts/thread register-resident, keeping the
// r9 tail (DPP max -> readlane -> rescan -> u64 LDS atomicMax -> ONE barrier
// -> kslot + pts[] fetch). Tests whether the ~1500cyc/step unexplained floor
// scales with tail fan-in (16->4 waves) or is wave-count-invariant.
// !! r7 LESSON: subtract-form distance with contract(off) is EXACT and
//    load-bearing. r10 LESSON: v_pk_*_f32 gives no VALU throughput on CDNA4
//    (2x cycles per inst) — scalar form is optimal.
// key = bits(wm)<<32 | (0xFFFFFFFF - j): u64 max == (max d, tie -> min j)
// == jnp.argmax first-max semantics (d >= 0). Slot rotation mod 3 race-free.
// ---------------------------------------------------------------------------
__global__ __launch_bounds__(256, 1) void fps_kernel(
    const float* __restrict__ pos,     // [B, N, 3]
    float* __restrict__ pos_s,         // [B, M, 3]
    float* __restrict__ batch_s)       // [B, M]
{
  const int b    = blockIdx.x;
  const int t    = threadIdx.x;
  const int lane = t & 63;
  const float* p = pos + (size_t)b * N_ * 3;

  for (int mm = t; mm < M_; mm += 256)
    batch_s[b * M_ + mm] = (float)b;

  __shared__ float4 pts[N_];                 // 128 KB: x,y,z,(unused)
  __shared__ unsigned long long kslot[3];
  if (t == 0) { kslot[0] = 0ull; kslot[1] = 0ull; kslot[2] = 0ull; }

  float px[32], py[32], pz[32], mind[32];
#pragma unroll
  for (int i = 0; i < 32; ++i) {
    int j = t + 256 * i;
    px[i] = p[j * 3 + 0];
    py[i] = p[j * 3 + 1];
    pz[i] = p[j * 3 + 2];
    mind[i] = 1e10f;
    pts[j] = make_float4(px[i], py[i], pz[i], 0.0f);
  }
#pragma unroll
  for (int i = 0; i < 32; ++i) {
    asm volatile("" : "+v"(px[i]), "+v"(py[i]), "+v"(pz[i]));
  }
  __syncthreads();   // pts[] visible to all

  float4 c0 = pts[0];
  float lx = c0.x, ly = c0.y, lz = c0.z;
  if (t == 0) {
    pos_s[(size_t)b * M_ * 3 + 0] = lx;
    pos_s[(size_t)b * M_ * 3 + 1] = ly;
    pos_s[(size_t)b * M_ * 3 + 2] = lz;
  }

  int sl = 1;   // s % 3
  int rs = 0;   // (s+2) % 3
  for (int s = 1; s < M_; ++s) {
    float tmax;
    {
#pragma clang fp contract(off)
#pragma unroll
      for (int i = 0; i < 32; ++i) {
        float dx = px[i] - lx, dy = py[i] - ly, dz = pz[i] - lz;
        float d  = (dx * dx + dy * dy) + dz * dz;   // EXACT: jnp sum order, no fma
        mind[i]  = fminf(mind[i], d);
      }
      float a[16];
#pragma unroll
      for (int q = 0; q < 16; ++q) a[q] = fmaxf(mind[2 * q], mind[2 * q + 1]);
#pragma unroll
      for (int q = 0; q < 8; ++q) a[q] = fmaxf(a[q], a[q + 8]);
#pragma unroll
      for (int q = 0; q < 4; ++q) a[q] = fmaxf(a[q], a[q + 4]);
      a[0] = fmaxf(a[0], a[2]); a[1] = fmaxf(a[1], a[3]);
      tmax = fmaxf(a[0], a[1]);
    }
    // wave max (VALU-pipe DPP): lane 63 ends with the full 64-lane max
    float w = tmax;
    w = dppmax<0x111>(w);   // row_shr:1
    w = dppmax<0x112>(w);   // row_shr:2
    w = dppmax<0x114>(w);   // row_shr:4
    w = dppmax<0x118>(w);   // row_shr:8
    w = dppmax<0x142>(w);   // row_bcast:15
    w = dppmax<0x143>(w);   // row_bcast:31
    const float wm = __int_as_float(
        __builtin_amdgcn_readlane(__float_as_int(w), 63));
    // rescan vs wave max, descending i -> smallest local index wins
    unsigned int jc = 0xFFFFFFFFu;
#pragma unroll
    for (int i = 31; i >= 0; --i)
      if (mind[i] == wm) jc = (unsigned int)(t + 256 * i);
    if (jc != 0xFFFFFFFFu) {   // ~1 lane per wave
      unsigned long long key =
          ((unsigned long long)__float_as_uint(wm) << 32) |
          (unsigned long long)(0xFFFFFFFFu - jc);
      atomicMax(&kslot[sl], key);
    }
    __syncthreads();                               // the ONE barrier
    if (t == 0) kslot[rs] = 0ull;
    const unsigned long long kk = kslot[sl];
    const int wj = (int)(0xFFFFFFFFu - (unsigned int)(kk & 0xFFFFFFFFull));
    const int wju = (int)__builtin_amdgcn_readfirstlane(wj);
    float4 wc = pts[wju];                          // broadcast ds_read_b128
    lx = wc.x; ly = wc.y; lz = wc.z;
    if (t == 0) {
      size_t o = ((size_t)b * M_ + s) * 3;
      pos_s[o + 0] = lx; pos_s[o + 1] = ly; pos_s[o + 2] = lz;
    }
    sl = (sl == 2) ? 0 : sl + 1;
    rs = (rs == 2) ? 0 : rs + 1;
  }
}

// ---------------------------------------------------------------------------
// Prep: transpose + fp16-convert weights into workspace (once per launch).
// ---------------------------------------------------------------------------
__global__ __launch_bounds__(256) void prep_kernel(
    const float* __restrict__ W1, const float* __restrict__ W2,
    _Float16* __restrict__ w1t, _Float16* __restrict__ w2t)
{
  int t = blockIdx.x * 256 + threadIdx.x;
  if (t < 8192) {
    int n = t >> 6, k = t & 63;
    w2t[t] = (_Float16)W2[k * 128 + n];
  }
  int u = t - 8192;
  if (u >= 0 && u < 1024) {
    int n = u >> 4, k = u & 15;
    w1t[u] = (_Float16)W1[k * 64 + n];
  }
}

// ---------------------------------------------------------------------------
// Kernel 2: ball query (exact fp32) + gather + MFMA fp16 MLP + masked max.
// UNCHANGED from round 9 (passed, absmax 0.0078, ~100 us).
// ---------------------------------------------------------------------------
__global__ __launch_bounds__(64) void sa_kernel(
    const float* __restrict__ x,       // [B, N, 13]
    const float* __restrict__ pos,     // [B, N, 3]
    const float* __restrict__ b1,      // [64]
    const float* __restrict__ b2,      // [128]
    const float* __restrict__ pos_s,   // [B, M, 3]
    const _Float16* __restrict__ w1t,  // [64][16]
    const _Float16* __restrict__ w2t,  // [128][64]
    float* __restrict__ x_out)         // [B, M, 128]
{
  const int blk  = blockIdx.x;
  const int b    = blk >> 11;          // / 2048
  const int m    = blk & 2047;
  const int lane = threadIdx.x;
  const int l15  = lane & 15;
  const int quad = lane >> 4;

  __shared__ int      nbr[K_];
  __shared__ _Float16 featb[K_][24];   // [32][16] + pad
  __shared__ _Float16 h1b[K_][72];     // [32][64] + pad (16-aligned rows)

  const float* pb = pos + (size_t)b * N_ * 3;
  const float* xb = x   + (size_t)b * N_ * DIN_;
  const size_t so = ((size_t)b * M_ + m) * 3;
  const float sx = pos_s[so + 0];
  const float sy = pos_s[so + 1];
  const float sz = pos_s[so + 2];
  const float R2 = (float)(0.2 * 0.2);

  // --- ball query: first K in-ball neighbors in index order (EXACT fp32) ---
  int cnt = 0;
  for (int base = 0; base < N_ && cnt < K_; base += 64) {
    int j = base + lane;
    float qx = pb[j * 3 + 0], qy = pb[j * 3 + 1], qz = pb[j * 3 + 2];
    bool win;
    {
#pragma clang fp contract(off)
      float dx = sx - qx, dy = sy - qy, dz = sz - qz;
      float d2 = (dx * dx + dy * dy) + dz * dz;
      win = d2 <= R2;
    }
    unsigned long long mk = __ballot(win);
    int rank = (int)__popcll(mk & ((1ull << lane) - 1ull));
    if (win) {
      int slot = cnt + rank;
      if (slot < K_) nbr[slot] = j;
    }
    cnt += (int)__popcll(mk);
  }
  const int valid = cnt < K_ ? cnt : K_;   // uniform across wave, >= 1
  __syncthreads();

  // --- gather -> featb (fp16): concat(x_j, pos_j - pos_s), invalid rows 0 ---
  for (int tq = lane; tq < K_ * 16; tq += 64) {
    int r = tq >> 4, i = tq & 15;
    float v = 0.f;
    if (r < valid) {
      int j = nbr[r];
      if (i < DIN_) {
        v = xb[j * DIN_ + i];
      } else {
        float c = (i == 13) ? sx : (i == 14) ? sy : sz;
        float q = pb[j * 3 + (i - 13)];
        v = q - c;
      }
    }
    featb[r][i] = (_Float16)v;
  }
  __syncthreads();

  f16x8 fz;
#pragma unroll
  for (int i = 0; i < 8; ++i) fz[i] = (_Float16)0;

  // --- A1 / B1 fragments (K=32, k>=16 zero-padded on BOTH operands) ---
  f16x8 a1[2], b1f[4];
#pragma unroll
  for (int mt = 0; mt < 2; ++mt)
    a1[mt] = (quad < 2) ? *(const f16x8*)&featb[mt * 16 + l15][quad * 8] : fz;
#pragma unroll
  for (int nt = 0; nt < 4; ++nt)
    b1f[nt] = (quad < 2) ? *(const f16x8*)&w1t[(nt * 16 + l15) * 16 + quad * 8]
                         : fz;

  // --- MLP1 MFMA + bias + relu -> h1b (fp16) ---
#pragma unroll
  for (int mt = 0; mt < 2; ++mt) {
#pragma unroll
    for (int nt = 0; nt < 4; ++nt) {
      f32x4 c = {0.f, 0.f, 0.f, 0.f};
      c = __builtin_amdgcn_mfma_f32_16x16x32_f16(a1[mt], b1f[nt], c, 0, 0, 0);
      float bb = b1[nt * 16 + l15];
#pragma unroll
      for (int r = 0; r < 4; ++r) {
        float v = c[r] + bb;
        h1b[mt * 16 + quad * 4 + r][nt * 16 + l15] =
            (_Float16)(v > 0.f ? v : 0.f);
      }
    }
  }
  __syncthreads();

  // --- A2 fragments from h1b ---
  f16x8 a2[2][2];
#pragma unroll
  for (int mt = 0; mt < 2; ++mt)
#pragma unroll
    for (int kt = 0; kt < 2; ++kt)
      a2[mt][kt] = *(const f16x8*)&h1b[mt * 16 + l15][kt * 32 + quad * 8];

  // --- MLP2 per N-tile: 4 MFMA + bias/relu/mask/max + cross-quad reduce ---
  float* o = x_out + ((size_t)b * M_ + m) * 128;
#pragma unroll
  for (int nt = 0; nt < 8; ++nt) {
    f16x8 b20 = *(const f16x8*)&w2t[(nt * 16 + l15) * 64 + 0 * 32 + quad * 8];
    f16x8 b21 = *(const f16x8*)&w2t[(nt * 16 + l15) * 64 + 1 * 32 + quad * 8];
    f32x4 c0 = {0.f, 0.f, 0.f, 0.f}, c1 = {0.f, 0.f, 0.f, 0.f};
    c0 = __builtin_amdgcn_mfma_f32_16x16x32_f16(a2[0][0], b20, c0, 0, 0, 0);
    c0 = __builtin_amdgcn_mfma_f32_16x16x32_f16(a2[0][1], b21, c0, 0, 0, 0);
    c1 = __builtin_amdgcn_mfma_f32_16x16x32_f16(a2[1][0], b20, c1, 0, 0, 0);
    c1 = __builtin_amdgcn_mfma_f32_16x16x32_f16(a2[1][1], b21, c1, 0, 0, 0);
    float bv = b2[nt * 16 + l15];
    float acc = -INFINITY;
#pragma unroll
    for (int r = 0; r < 4; ++r) {
      int row0 = quad * 4 + r;          // rows 0..15  (c0)
      int row1 = 16 + quad * 4 + r;     // rows 16..31 (c1)
      float v0 = c0[r] + bv; v0 = v0 > 0.f ? v0 : 0.f;
      float v1 = c1[r] + bv; v1 = v1 > 0.f ? v1 : 0.f;
      if (row0 < valid) acc = fmaxf(acc, v0);
      if (row1 < valid) acc = fmaxf(acc, v1);
    }
    acc = fmaxf(acc, __shfl_xor(acc, 16));
    acc = fmaxf(acc, __shfl_xor(acc, 32));
    if (quad == 0) o[nt * 16 + l15] = acc;
  }
}

// ---------------------------------------------------------------------------
extern "C" void kernel_launch(void* const* d_in, const int* in_sizes, int n_in,
                              void* d_out, int out_size, void* d_ws, size_t ws_size,
                              hipStream_t stream) {
  (void)in_sizes; (void)n_in; (void)ws_size; (void)out_size;
  const float* x   = (const float*)d_in[0];
  const float* pos = (const float*)d_in[1];
  // d_in[2] = batch (unused: always broadcast arange(B))
  const float* W1  = (const float*)d_in[3];
  const float* b1  = (const float*)d_in[4];
  const float* W2  = (const float*)d_in[5];
  const float* b2  = (const float*)d_in[6];

  float* out     = (float*)d_out;
  float* x_out   = out;                                  // [B, M, 128]
  float* pos_s   = out + (size_t)B_ * M_ * 128;          // [B, M, 3]
  float* batch_s = pos_s + (size_t)B_ * M_ * 3;          // [B, M]

  _Float16* w1t = (_Float16*)d_ws;                       // [64][16]
  _Float16* w2t = w1t + 1024;                            // [128][64]

  prep_kernel<<<36, 256, 0, stream>>>(W1, W2, w1t, w2t);
  fps_kernel<<<B_, 256, 0, stream>>>(pos, pos_s, batch_s);
  sa_kernel<<<B_ * M_, 64, 0, stream>>>(x, pos, b1, b2, pos_s, w1t, w2t, x_out);
}

// Round 12
// 2267.119 us; speedup vs baseline: 1.0506x; 1.0506x over previous
//
#include <hip/hip_runtime.h>
#include <cstddef>

#define B_   8
#define N_   8192
#define M_   2048
#define K_   32
#define DIN_ 13

typedef _Float16 f16x8 __attribute__((ext_vector_type(8)));
typedef float    f32x4 __attribute__((ext_vector_type(4)));

// DPP-assisted max step: combine v with the value DPP-moved from another lane.
// Invalid source lanes yield old = -inf (identity for max). VALU-pipe only.
template <int CTRL>
__device__ __forceinline__ float dppmax(float v) {
  int o = __builtin_amdgcn_update_dpp(
      (int)0xff800000, __float_as_int(v), CTRL, 0xF, 0xF, false);
  return fmaxf(v, __int_as_float(o));
}

__device__ __forceinline__ float max3f(float a, float b, float c) {
  float d;
  asm("v_max3_f32 %0, %1, %2, %3" : "=v"(d) : "v"(a), "v"(b), "v"(c));
  return d;
}

// ---------------------------------------------------------------------------
// Kernel 1: farthest point sampling — r9 configuration restored (best
// measured: 2155 us steady), + v_max3_f32 in-thread max tree (bit-exact:
// max over a set is order-invariant for non-NaN inputs).
// LESSONS LOCKED IN:
//  r7: subtract-form distance with contract(off) is EXACT and load-bearing;
//      dot-form (|p|^2+|l|^2-2p.l) flips argmax selections. Never change.
//  r10: v_pk_*_f32 gives no VALU throughput on CDNA4 (2x cyc/inst).
//  r11: per-step floor (~1.05 us) is wave-count invariant — serial-latency
//      chain, not issue/fan-in. 1024 thr / 8 pts is the sweet spot.
// Per step (ONE barrier):
//   dist+min update -> thread max3 tree -> wave DPP max -> readlane(63) ->
//   rescan mind==wm (exact) -> candidate lane (~1/wave) atomicMax(u64 key)
//   into kslot[s%3] -> barrier -> read kslot, extract j, ds_read_b128 coords.
// key = bits(wm)<<32 | (0xFFFFFFFF - j): u64 max == (max d, tie -> min j)
// == jnp.argmax first-max semantics (d >= 0). Slot rotation mod 3 race-free.
// ---------------------------------------------------------------------------
__global__ __launch_bounds__(1024, 4) void fps_kernel(
    const float* __restrict__ pos,     // [B, N, 3]
    float* __restrict__ pos_s,         // [B, M, 3]
    float* __restrict__ batch_s)       // [B, M]
{
  const int b    = blockIdx.x;
  const int t    = threadIdx.x;
  const int lane = t & 63;
  const float* p = pos + (size_t)b * N_ * 3;

  for (int mm = t; mm < M_; mm += 1024)
    batch_s[b * M_ + mm] = (float)b;

  __shared__ float4 pts[N_];                 // 128 KB: x,y,z,(unused)
  __shared__ unsigned long long kslot[3];
  if (t == 0) { kslot[0] = 0ull; kslot[1] = 0ull; kslot[2] = 0ull; }

  float px[8], py[8], pz[8], mind[8];
#pragma unroll
  for (int i = 0; i < 8; ++i) {
    int j = t + 1024 * i;
    px[i] = p[j * 3 + 0];
    py[i] = p[j * 3 + 1];
    pz[i] = p[j * 3 + 2];
    mind[i] = 1e10f;
    pts[j] = make_float4(px[i], py[i], pz[i], 0.0f);
  }
#pragma unroll
  for (int i = 0; i < 8; ++i) {
    asm volatile("" : "+v"(px[i]), "+v"(py[i]), "+v"(pz[i]));
  }
  __syncthreads();   // pts[] visible to all

  float4 c0 = pts[0];
  float lx = c0.x, ly = c0.y, lz = c0.z;
  if (t == 0) {
    pos_s[(size_t)b * M_ * 3 + 0] = lx;
    pos_s[(size_t)b * M_ * 3 + 1] = ly;
    pos_s[(size_t)b * M_ * 3 + 2] = lz;
  }

  int sl = 1;   // s % 3
  int rs = 0;   // (s+2) % 3
  for (int s = 1; s < M_; ++s) {
    float tmax;
    {
#pragma clang fp contract(off)
#pragma unroll
      for (int i = 0; i < 8; ++i) {
        float dx = px[i] - lx, dy = py[i] - ly, dz = pz[i] - lz;
        float d  = (dx * dx + dy * dy) + dz * dz;   // EXACT: jnp sum order, no fma
        mind[i]  = fminf(mind[i], d);
      }
      // 8-way max via v_max3 (selection — order-invariant, bit-exact)
      float u0 = max3f(mind[0], mind[1], mind[2]);
      float u1 = max3f(mind[3], mind[4], mind[5]);
      float u2 = fmaxf(mind[6], mind[7]);
      tmax = max3f(u0, u1, u2);
    }
    // wave max (VALU-pipe DPP): lane 63 ends with the full 64-lane max
    float w = tmax;
    w = dppmax<0x111>(w);   // row_shr:1
    w = dppmax<0x112>(w);   // row_shr:2
    w = dppmax<0x114>(w);   // row_shr:4
    w = dppmax<0x118>(w);   // row_shr:8
    w = dppmax<0x142>(w);   // row_bcast:15
    w = dppmax<0x143>(w);   // row_bcast:31
    const float wm = __int_as_float(
        __builtin_amdgcn_readlane(__float_as_int(w), 63));
    // rescan vs wave max, descending i -> smallest local index wins
    unsigned int jc = 0xFFFFFFFFu;
#pragma unroll
    for (int i = 7; i >= 0; --i)
      if (mind[i] == wm) jc = (unsigned int)(t + 1024 * i);
    if (jc != 0xFFFFFFFFu) {   // ~1 lane per wave
      unsigned long long key =
          ((unsigned long long)__float_as_uint(wm) << 32) |
          (unsigned long long)(0xFFFFFFFFu - jc);
      atomicMax(&kslot[sl], key);
    }
    __syncthreads();                               // the ONE barrier
    if (t == 0) kslot[rs] = 0ull;
    const unsigned long long kk = kslot[sl];
    const int wj = (int)(0xFFFFFFFFu - (unsigned int)(kk & 0xFFFFFFFFull));
    const int wju = (int)__builtin_amdgcn_readfirstlane(wj);
    float4 wc = pts[wju];                          // broadcast ds_read_b128
    lx = wc.x; ly = wc.y; lz = wc.z;
    if (t == 0) {
      size_t o = ((size_t)b * M_ + s) * 3;
      pos_s[o + 0] = lx; pos_s[o + 1] = ly; pos_s[o + 2] = lz;
    }
    sl = (sl == 2) ? 0 : sl + 1;
    rs = (rs == 2) ? 0 : rs + 1;
  }
}

// ---------------------------------------------------------------------------
// Prep: transpose + fp16-convert weights into workspace (once per launch).
// ---------------------------------------------------------------------------
__global__ __launch_bounds__(256) void prep_kernel(
    const float* __restrict__ W1, const float* __restrict__ W2,
    _Float16* __restrict__ w1t, _Float16* __restrict__ w2t)
{
  int t = blockIdx.x * 256 + threadIdx.x;
  if (t < 8192) {
    int n = t >> 6, k = t & 63;
    w2t[t] = (_Float16)W2[k * 128 + n];
  }
  int u = t - 8192;
  if (u >= 0 && u < 1024) {
    int n = u >> 4, k = u & 15;
    w1t[u] = (_Float16)W1[k * 64 + n];
  }
}

// ---------------------------------------------------------------------------
// Kernel 2: ball query (exact fp32) + gather + MFMA fp16 MLP + masked max.
// UNCHANGED from round 9 (passed, absmax 0.0078, ~100 us).
// ---------------------------------------------------------------------------
__global__ __launch_bounds__(64) void sa_kernel(
    const float* __restrict__ x,       // [B, N, 13]
    const float* __restrict__ pos,     // [B, N, 3]
    const float* __restrict__ b1,      // [64]
    const float* __restrict__ b2,      // [128]
    const float* __restrict__ pos_s,   // [B, M, 3]
    const _Float16* __restrict__ w1t,  // [64][16]
    const _Float16* __restrict__ w2t,  // [128][64]
    float* __restrict__ x_out)         // [B, M, 128]
{
  const int blk  = blockIdx.x;
  const int b    = blk >> 11;          // / 2048
  const int m    = blk & 2047;
  const int lane = threadIdx.x;
  const int l15  = lane & 15;
  const int quad = lane >> 4;

  __shared__ int      nbr[K_];
  __shared__ _Float16 featb[K_][24];   // [32][16] + pad
  __shared__ _Float16 h1b[K_][72];     // [32][64] + pad (16-aligned rows)

  const float* pb = pos + (size_t)b * N_ * 3;
  const float* xb = x   + (size_t)b * N_ * DIN_;
  const size_t so = ((size_t)b * M_ + m) * 3;
  const float sx = pos_s[so + 0];
  const float sy = pos_s[so + 1];
  const float sz = pos_s[so + 2];
  const float R2 = (float)(0.2 * 0.2);

  // --- ball query: first K in-ball neighbors in index order (EXACT fp32) ---
  int cnt = 0;
  for (int base = 0; base < N_ && cnt < K_; base += 64) {
    int j = base + lane;
    float qx = pb[j * 3 + 0], qy = pb[j * 3 + 1], qz = pb[j * 3 + 2];
    bool win;
    {
#pragma clang fp contract(off)
      float dx = sx - qx, dy = sy - qy, dz = sz - qz;
      float d2 = (dx * dx + dy * dy) + dz * dz;
      win = d2 <= R2;
    }
    unsigned long long mk = __ballot(win);
    int rank = (int)__popcll(mk & ((1ull << lane) - 1ull));
    if (win) {
      int slot = cnt + rank;
      if (slot < K_) nbr[slot] = j;
    }
    cnt += (int)__popcll(mk);
  }
  const int valid = cnt < K_ ? cnt : K_;   // uniform across wave, >= 1
  __syncthreads();

  // --- gather -> featb (fp16): concat(x_j, pos_j - pos_s), invalid rows 0 ---
  for (int tq = lane; tq < K_ * 16; tq += 64) {
    int r = tq >> 4, i = tq & 15;
    float v = 0.f;
    if (r < valid) {
      int j = nbr[r];
      if (i < DIN_) {
        v = xb[j * DIN_ + i];
      } else {
        float c = (i == 13) ? sx : (i == 14) ? sy : sz;
        float q = pb[j * 3 + (i - 13)];
        v = q - c;
      }
    }
    featb[r][i] = (_Float16)v;
  }
  __syncthreads();

  f16x8 fz;
#pragma unroll
  for (int i = 0; i < 8; ++i) fz[i] = (_Float16)0;

  // --- A1 / B1 fragments (K=32, k>=16 zero-padded on BOTH operands) ---
  f16x8 a1[2], b1f[4];
#pragma unroll
  for (int mt = 0; mt < 2; ++mt)
    a1[mt] = (quad < 2) ? *(const f16x8*)&featb[mt * 16 + l15][quad * 8] : fz;
#pragma unroll
  for (int nt = 0; nt < 4; ++nt)
    b1f[nt] = (quad < 2) ? *(const f16x8*)&w1t[(nt * 16 + l15) * 16 + quad * 8]
                         : fz;

  // --- MLP1 MFMA + bias + relu -> h1b (fp16) ---
#pragma unroll
  for (int mt = 0; mt < 2; ++mt) {
#pragma unroll
    for (int nt = 0; nt < 4; ++nt) {
      f32x4 c = {0.f, 0.f, 0.f, 0.f};
      c = __builtin_amdgcn_mfma_f32_16x16x32_f16(a1[mt], b1f[nt], c, 0, 0, 0);
      float bb = b1[nt * 16 + l15];
#pragma unroll
      for (int r = 0; r < 4; ++r) {
        float v = c[r] + bb;
        h1b[mt * 16 + quad * 4 + r][nt * 16 + l15] =
            (_Float16)(v > 0.f ? v : 0.f);
      }
    }
  }
  __syncthreads();

  // --- A2 fragments from h1b ---
  f16x8 a2[2][2];
#pragma unroll
  for (int mt = 0; mt < 2; ++mt)
#pragma unroll
    for (int kt = 0; kt < 2; ++kt)
      a2[mt][kt] = *(const f16x8*)&h1b[mt * 16 + l15][kt * 32 + quad * 8];

  // --- MLP2 per N-tile: 4 MFMA + bias/relu/mask/max + cross-quad reduce ---
  float* o = x_out + ((size_t)b * M_ + m) * 128;
#pragma unroll
  for (int nt = 0; nt < 8; ++nt) {
    f16x8 b20 = *(const f16x8*)&w2t[(nt * 16 + l15) * 64 + 0 * 32 + quad * 8];
    f16x8 b21 = *(const f16x8*)&w2t[(nt * 16 + l15) * 64 + 1 * 32 + quad * 8];
    f32x4 c0 = {0.f, 0.f, 0.f, 0.f}, c1 = {0.f, 0.f, 0.f, 0.f};
    c0 = __builtin_amdgcn_mfma_f32_16x16x32_f16(a2[0][0], b20, c0, 0, 0, 0);
    c0 = __builtin_amdgcn_mfma_f32_16x16x32_f16(a2[0][1], b21, c0, 0, 0, 0);
    c1 = __builtin_amdgcn_mfma_f32_16x16x32_f16(a2[1][0], b20, c1, 0, 0, 0);
    c1 = __builtin_amdgcn_mfma_f32_16x16x32_f16(a2[1][1], b21, c1, 0, 0, 0);
    float bv = b2[nt * 16 + l15];
    float acc = -INFINITY;
#pragma unroll
    for (int r = 0; r < 4; ++r) {
      int row0 = quad * 4 + r;          // rows 0..15  (c0)
      int row1 = 16 + quad * 4 + r;     // rows 16..31 (c1)
      float v0 = c0[r] + bv; v0 = v0 > 0.f ? v0 : 0.f;
      float v1 = c1[r] + bv; v1 = v1 > 0.f ? v1 : 0.f;
      if (row0 < valid) acc = fmaxf(acc, v0);
      if (row1 < valid) acc = fmaxf(acc, v1);
    }
    acc = fmaxf(acc, __shfl_xor(acc, 16));
    acc = fmaxf(acc, __shfl_xor(acc, 32));
    if (quad == 0) o[nt * 16 + l15] = acc;
  }
}

// ---------------------------------------------------------------------------
extern "C" void kernel_launch(void* const* d_in, const int* in_sizes, int n_in,
                              void* d_out, int out_size, void* d_ws, size_t ws_size,
                              hipStream_t stream) {
  (void)in_sizes; (void)n_in; (void)ws_size; (void)out_size;
  const float* x   = (const float*)d_in[0];
  const float* pos = (const float*)d_in[1];
  // d_in[2] = batch (unused: always broadcast arange(B))
  const float* W1  = (const float*)d_in[3];
  const float* b1  = (const float*)d_in[4];
  const float* W2  = (const float*)d_in[5];
  const float* b2  = (const float*)d_in[6];

  float* out     = (float*)d_out;
  float* x_out   = out;                                  // [B, M, 128]
  float* pos_s   = out + (size_t)B_ * M_ * 128;          // [B, M, 3]
  float* batch_s = pos_s + (size_t)B_ * M_ * 3;          // [B, M]

  _Float16* w1t = (_Float16*)d_ws;                       // [64][16]
  _Float16* w2t = w1t + 1024;                            // [128][64]

  prep_kernel<<<36, 256, 0, stream>>>(W1, W2, w1t, w2t);
  fps_kernel<<<B_, 1024, 0, stream>>>(pos, pos_s, batch_s);
  sa_kernel<<<B_ * M_, 64, 0, stream>>>(x, pos, b1, b2, pos_s, w1t, w2t, x_out);
}